// Round 5
// baseline (635.019 us; speedup 1.0000x reference)
//
#include <hip/hip_runtime.h>

typedef _Float16 f16;
typedef __attribute__((ext_vector_type(8))) _Float16 half8;
typedef __attribute__((ext_vector_type(4))) float floatx4;

#define BB   16
#define TSN  16
#define NNP  4096
#define HID  64
#define KPK  224      // 6 k-tiles of 32 (h taps) + 1 k-tile (x taps, 3 live)
#define MBLK 128      // positions per block
#define NROW 130      // MBLK + 2 halo rows
#define NTIL 32       // tiles per batch
#define NBLK 512      // total blocks

// LDS physical layout: row stride 64 f16 (32 dw, == 0 mod 32 banks), chunk
// (16B group of 8 f16) XOR-swizzled by row: phys_chunk = chunk ^ (row & 7).
// -> b128 A-reads have the same bank distribution as stride-1 (balanced,
//    conflict-free); dword epilogue writes are 2-way (free).
__device__ __forceinline__ int hadr(int rr, int c) {   // f16 index
    return rr * 64 + ((c ^ (rr & 7)) << 3);
}
__device__ __forceinline__ unsigned f16pair(float a, float b) {
    union { f16 h; unsigned short u; } ua, ub;
    ua.h = (f16)a; ub.h = (f16)b;
    return (unsigned)ua.u | ((unsigned)ub.u << 16);
}

// ---------------------------------------------------------------------------
// Pack conv_w (OIHW 256x65x3x3, only kw=1 live) -> f16 wpack[oc][k]:
//   k = kt*32+c;  kt<6: tap=kt>>1, ch j=(kt&1)*32+c;  kt=6: c<3 -> x tap c.
// ---------------------------------------------------------------------------
__global__ void pack_w_kernel(const float* __restrict__ conv_w, f16* __restrict__ wpack) {
    int idx = blockIdx.x * 256 + threadIdx.x;
    if (idx >= 4 * 64 * KPK) return;
    int k  = idx % KPK;
    int oc = idx / KPK;
    int kt = k >> 5, c = k & 31;
    float w = 0.0f;
    if (kt < 6) {
        int tap = kt >> 1;
        int j   = (kt & 1) * 32 + c;
        w = conv_w[((oc * 65 + 1 + j) * 3 + tap) * 3 + 1];
    } else if (c < 3) {
        w = conv_w[((oc * 65 + 0) * 3 + c) * 3 + 1];
    }
    wpack[oc * KPK + k] = (f16)w;
}

__global__ void zero_flags_kernel(int* __restrict__ progress) {
    if (threadIdx.x < NBLK) progress[threadIdx.x] = 0;
}

__device__ __forceinline__ float sigmoid_f(float v) { return 1.0f / (1.0f + __expf(-v)); }
__device__ __forceinline__ float tanh_f(float v) { float e = __expf(2.0f * v); return 1.0f - 2.0f / (e + 1.0f); }

// ---------------------------------------------------------------------------
// Persistent ConvLSTM, neighbor-flag synchronized (no grid barrier).
// Block = 256 thr (4 waves), batch b, positions [n0, n0+128). Wave w: hid
// [w*16,w*16+16) x 4 gates -> lane-local epilogue. Double-buffered swizzled
// hlds; c and all weights live in registers for all 16 steps.
// Boundary exchange: 2 rows/block/step through parity-double-buffered global
// slots + release/acquire progress flags (left/right neighbors only).
// coop=0 fallback: one launch per step, h/c round-trip via global.
// ---------------------------------------------------------------------------
__global__ __launch_bounds__(256, 2)
void lstm_kernel(const float* __restrict__ x, const f16* __restrict__ wpack,
                 const float* __restrict__ conv_b,
                 const f16* __restrict__ h_in, f16* __restrict__ h_out,
                 float* __restrict__ c_glob,
                 int* __restrict__ progress, unsigned* __restrict__ hb,
                 int t0, int t1, int coop)
{
    __shared__ __align__(16) f16 hlds[2][NROW * 64];
    __shared__ __align__(16) f16 xt[MBLK * 64];

    const int blk  = blockIdx.x;
    const int b    = blk >> 5;
    const int tau  = blk & 31;
    const int n0   = tau * MBLK;
    const int tid  = threadIdx.x;
    const int lane = tid & 63;
    const int wave = tid >> 6;
    const int m    = lane & 15;
    const int kg   = lane >> 4;
    const int hid_col = wave * 16 + m;

    // B fragments: 7 k-tiles x 4 gates, resident for all steps
    half8 bf[7][4];
#pragma unroll
    for (int kt = 0; kt < 7; ++kt)
#pragma unroll
        for (int g = 0; g < 4; ++g)
            bf[kt][g] = *(const half8*)(wpack + (g * 64 + hid_col) * KPK + kt * 32 + kg * 8);

    float bias[4];
#pragma unroll
    for (int g = 0; g < 4; ++g) bias[g] = conv_b[g * 64 + hid_col];

    // c in registers: creg[pass*16+ms*4+r] <-> pos n0+pass*64+ms*16+kg*4+r
    float creg[32];
#pragma unroll
    for (int i = 0; i < 32; ++i) creg[i] = 0.0f;
    if (!coop && t0 > 0) {
#pragma unroll
        for (int pass = 0; pass < 2; ++pass)
#pragma unroll
            for (int ms = 0; ms < 4; ++ms)
#pragma unroll
                for (int r = 0; r < 4; ++r) {
                    int pos = n0 + pass * 64 + ms * 16 + kg * 4 + r;
                    creg[pass * 16 + ms * 4 + r] = c_glob[(size_t)(b * NNP + pos) * HID + hid_col];
                }
    }

    // zero LDS (halo rows of both buffers + xt cols>=3 must be zero)
    for (int i = tid; i < NROW * 64; i += 256) { hlds[0][i] = (f16)0; hlds[1][i] = (f16)0; }
    for (int i = tid; i < MBLK * 64; i += 256) xt[i] = (f16)0;
    __syncthreads();

#pragma unroll 1
    for (int t = t0; t < t1; ++t) {
        const int p = coop ? (t & 1) : 0;
        const f16* hrd = hlds[p];
        f16*       hwr = hlds[p ^ 1];

        // ---- stage h(t-1) ----
        if (t > 0) {
            if (coop) {
                // wait for neighbors to have completed step t-1 (flag >= t)
                if (tau > 0 && tid == 0)
                    while (__hip_atomic_load(&progress[blk - 1], __ATOMIC_ACQUIRE,
                                             __HIP_MEMORY_SCOPE_AGENT) < t)
                        __builtin_amdgcn_s_sleep(1);
                if (tau < NTIL - 1 && tid == 32)
                    while (__hip_atomic_load(&progress[blk + 1], __ATOMIC_ACQUIRE,
                                             __HIP_MEMORY_SCOPE_AGENT) < t)
                        __builtin_amdgcn_s_sleep(1);
                // halo rows 0 / 129 from neighbors' parity slots
                if (tid < 64) {
                    int side = tid >> 5;            // 0: left halo, 1: right halo
                    int q    = tid & 31;
                    bool have = side ? (tau < NTIL - 1) : (tau > 0);
                    if (have) {
                        int nbr  = side ? (blk + 1) : (blk - 1);
                        int slot = side ? 0 : 1;    // right's first row / left's last row
                        int par  = (t - 1) & 1;
                        unsigned v = __hip_atomic_load(
                            &hb[((par * NBLK + nbr) * 2 + slot) * 32 + q],
                            __ATOMIC_RELAXED, __HIP_MEMORY_SCOPE_AGENT);
                        int rr = side ? (NROW - 1) : 0;
                        ((unsigned*)hrd)[rr * 32 + ((q >> 2) ^ (rr & 7)) * 4 + (q & 3)] = v;
                    }
                }
            } else {
                for (int idx = tid; idx < NROW * 8; idx += 256) {
                    int rr = idx >> 3, c = idx & 7;
                    int n  = n0 - 1 + rr;
                    half8 v = {};
                    if (n >= 0 && n < NNP)
                        v = *(const half8*)(h_in + (size_t)(b * NNP + n) * HID + c * 8);
                    *(half8*)((f16*)hrd + hadr(rr, c)) = v;
                }
            }
        }
        {   // x window: logical cols 0..2 of row r (chunk 0), rest stays zero
            const float* xb = x + ((size_t)b * TSN + t) * NNP;
            for (int r = tid; r < MBLK; r += 256) {
                int pp = n0 + r;
                float v0 = (pp >= 1) ? xb[pp - 1] : 0.0f;
                float v1 = xb[pp];
                float v2 = (pp + 1 < NNP) ? xb[pp + 1] : 0.0f;
                int base = hadr(r, 0);
                ((unsigned*)xt)[base >> 1] = f16pair(v0, v1);
                xt[base + 2] = (f16)v2;
            }
        }
        __syncthreads();   // barrier 1: staging done

#pragma unroll
        for (int pass = 0; pass < 2; ++pass) {
            const int rbase = pass * 64;
#pragma unroll
            for (int ms = 0; ms < 4; ++ms) {
                const int ar = rbase + ms * 16 + m;   // position-row of this lane

                floatx4 acc[4];
#pragma unroll
                for (int g = 0; g < 4; ++g) acc[g] = (floatx4){0.f, 0.f, 0.f, 0.f};

#pragma unroll
                for (int kt = 0; kt < 6; ++kt) {
                    int rr = ar + (kt >> 1);
                    half8 a = *(const half8*)(hrd + hadr(rr, (kt & 1) * 4 + kg));
#pragma unroll
                    for (int g = 0; g < 4; ++g)
                        acc[g] = __builtin_amdgcn_mfma_f32_16x16x32_f16(a, bf[kt][g], acc[g], 0, 0, 0);
                }
                {
                    half8 a = *(const half8*)(xt + hadr(ar, kg));
#pragma unroll
                    for (int g = 0; g < 4; ++g)
                        acc[g] = __builtin_amdgcn_mfma_f32_16x16x32_f16(a, bf[6][g], acc[g], 0, 0, 0);
                }

                // epilogue: lane owns (4 rows, hid_col, all gates)
#pragma unroll
                for (int r = 0; r < 4; ++r) {
                    int ridx = pass * 16 + ms * 4 + r;
                    float gi = acc[0][r] + bias[0];
                    float gf = acc[1][r] + bias[1];
                    float go = acc[2][r] + bias[2];
                    float gg = acc[3][r] + bias[3];
                    float cn = sigmoid_f(gf) * creg[ridx] + sigmoid_f(gi) * tanh_f(gg);
                    float hnf = sigmoid_f(go) * tanh_f(cn);
                    creg[ridx] = cn;
                    int rit = ms * 16 + kg * 4 + r;       // row within this pass
                    float po = __shfl_xor(hnf, 1);        // partner (hid_col^1) value
                    if (coop) {
                        if (!(m & 1)) {                   // even lane writes packed dword
                            int rr = rbase + rit + 1;
                            int c  = hid_col >> 3;
                            ((unsigned*)hwr)[rr * 32 + (c ^ (rr & 7)) * 4 + ((m & 7) >> 1)] =
                                f16pair(hnf, po);
                        }
                    } else {
                        h_out[(size_t)(b * NNP + n0 + rbase + rit) * HID + hid_col] = (f16)hnf;
                    }
                }
            }
        }

        if (coop) {
            __syncthreads();   // barrier 2: hwr complete, xt reads done
            if (t + 1 < t1) {
                // publish boundary rows (rr=1 -> slot0, rr=128 -> slot1)
                if (tid < 64) {
                    int side = tid >> 5;
                    int q    = tid & 31;
                    int rr   = side ? (NROW - 2) : 1;
                    unsigned v = ((const unsigned*)hwr)[rr * 32 + ((q >> 2) ^ (rr & 7)) * 4 + (q & 3)];
                    __hip_atomic_store(&hb[(((t & 1) * NBLK + blk) * 2 + side) * 32 + q], v,
                                       __ATOMIC_RELAXED, __HIP_MEMORY_SCOPE_AGENT);
                }
                if (tid == 0)
                    __hip_atomic_store(&progress[blk], t + 1,
                                       __ATOMIC_RELEASE, __HIP_MEMORY_SCOPE_AGENT);
            }
        }
    }

    if (coop) {
        // final h -> global, coalesced (wave writes 1 KiB contiguous)
        const f16* hf = hlds[((t1 - 1) & 1) ^ 1];
        for (int i = tid; i < MBLK * 8; i += 256) {
            int row = i >> 3, c = i & 7;
            half8 v = *(const half8*)(hf + hadr(row + 1, c));
            *(half8*)(h_out + (size_t)(b * NNP + n0 + row) * HID + c * 8) = v;
        }
    } else {
#pragma unroll
        for (int pass = 0; pass < 2; ++pass)
#pragma unroll
            for (int ms = 0; ms < 4; ++ms)
#pragma unroll
                for (int r = 0; r < 4; ++r) {
                    int pos = n0 + pass * 64 + ms * 16 + kg * 4 + r;
                    c_glob[(size_t)(b * NNP + pos) * HID + hid_col] = creg[pass * 16 + ms * 4 + r];
                }
    }
}

// ---------------------------------------------------------------------------
// fc: out[b,t,n] = sum_hid h[b][n][hid]*fc_w[hid] + fc_b, broadcast over t
// ---------------------------------------------------------------------------
__global__ void fc_kernel(const f16* __restrict__ h, const float* __restrict__ fc_w,
                          const float* __restrict__ fc_b, float* __restrict__ out) {
    int idx = blockIdx.x * 256 + threadIdx.x;      // b*NNP + n
    const half8* hp = (const half8*)(h + (size_t)idx * HID);
    float s = 0.0f;
#pragma unroll
    for (int q = 0; q < 8; ++q) {
        half8 v = hp[q];
#pragma unroll
        for (int e = 0; e < 8; ++e) s += (float)v[e] * fc_w[q * 8 + e];
    }
    s += fc_b[0];
    int b = idx >> 12, n = idx & (NNP - 1);
#pragma unroll
    for (int t = 0; t < TSN; ++t) out[((size_t)b * TSN + t) * NNP + n] = s;
}

extern "C" void kernel_launch(void* const* d_in, const int* in_sizes, int n_in,
                              void* d_out, int out_size, void* d_ws, size_t ws_size,
                              hipStream_t stream) {
    const float* x      = (const float*)d_in[0];
    const float* conv_w = (const float*)d_in[1];
    const float* conv_b = (const float*)d_in[2];
    const float* fc_w   = (const float*)d_in[3];
    const float* fc_b   = (const float*)d_in[4];
    float* out = (float*)d_out;

    char* ws = (char*)d_ws;
    const size_t hbytes = (size_t)BB * NNP * HID * sizeof(f16);     // 8.39 MB
    f16*      wpack    = (f16*)ws;                                  // 112 KiB
    f16*      h_a      = (f16*)(ws + 131072);
    f16*      h_b      = (f16*)(ws + 131072 + hbytes);
    float*    c_glob   = (float*)(ws + 131072 + 2 * hbytes);        // 16.8 MB, fallback only
    int*      progress = (int*)(ws + 131072 + 2 * hbytes + (size_t)BB * NNP * HID * 4);
    unsigned* hb       = (unsigned*)((char*)progress + 4096);       // 2*512*2*32*4 = 256 KiB

    pack_w_kernel<<<(4 * 64 * KPK + 255) / 256, 256, 0, stream>>>(conv_w, wpack);
    zero_flags_kernel<<<1, NBLK, 0, stream>>>(progress);

    int dev = 0;
    hipGetDevice(&dev);
    int coopAttr = 0, smCount = 0, nb = 0;
    hipDeviceGetAttribute(&coopAttr, hipDeviceAttributeCooperativeLaunch, dev);
    hipDeviceGetAttribute(&smCount, hipDeviceAttributeMultiprocessorCount, dev);
    hipOccupancyMaxActiveBlocksPerMultiprocessor(&nb, (const void*)lstm_kernel, 256, 0);

    bool coop = (coopAttr != 0) && ((long)nb * smCount >= NBLK);
    if (coop) {
        int t0 = 0, t1 = TSN, cf = 1;
        const f16* hi = h_a; f16* ho = h_a;
        void* args[] = {(void*)&x, (void*)&wpack, (void*)&conv_b,
                        (void*)&hi, (void*)&ho, (void*)&c_glob,
                        (void*)&progress, (void*)&hb,
                        (void*)&t0, (void*)&t1, (void*)&cf};
        hipError_t e = hipLaunchCooperativeKernel((const void*)lstm_kernel,
                                                  dim3(NBLK), dim3(256), args, 0, stream);
        if (e != hipSuccess) coop = false;
    }
    if (!coop) {
        for (int t = 0; t < TSN; ++t) {
            const f16* hi = (t & 1) ? h_b : h_a;
            f16*       ho = (t & 1) ? h_a : h_b;   // t=15 -> h_a; fc reads h_a
            lstm_kernel<<<NBLK, 256, 0, stream>>>(x, wpack, conv_b, hi, ho, c_glob,
                                                  progress, hb, t, t + 1, 0);
        }
    }

    fc_kernel<<<BB * NNP / 256, 256, 0, stream>>>(h_a, fc_w, fc_b, out);
}

// Round 6
// 383.417 us; speedup vs baseline: 1.6562x; 1.6562x over previous
//
#include <hip/hip_runtime.h>

typedef _Float16 f16;
typedef __attribute__((ext_vector_type(8))) _Float16 half8;
typedef __attribute__((ext_vector_type(4))) float floatx4;

#define BB    16
#define TSN   16
#define NNP   4096
#define HID   64
#define KPK   224     // 6 k-tiles of 32 (h taps) + 1 k-tile (x taps, 3 live)
#define WOUT  128     // valid output positions per block
#define HALO  16      // time-halo: redundant compute, shrinks 1/step
#define WCMP  160     // computed rows per step = WOUT + 2*HALO (10 m-tiles)
#define HROWS 162     // h-buffer rows = WCMP + 2 (conv halo)
#define NTIL  32

// LDS h layout: row stride 64 f16 (128 B == 0 mod 32 banks), 16B chunk
// XOR-swizzled by row (phys_chunk = chunk ^ (row&7)) -> b128 reads balanced
// (8 dw/bank minimum), dword epilogue writes 2-way (free). [verified R5:
// SQ_LDS_BANK_CONFLICT 8.3M -> 229K]
__device__ __forceinline__ int hadr(int rr, int c) {   // f16 index
    return rr * 64 + ((c ^ (rr & 7)) << 3);
}
__device__ __forceinline__ unsigned f16pair(float a, float b) {
    union { f16 h; unsigned short u; } ua, ub;
    ua.h = (f16)a; ub.h = (f16)b;
    return (unsigned)ua.u | ((unsigned)ub.u << 16);
}

// ---------------------------------------------------------------------------
// Pack conv_w (OIHW 256x65x3x3, only kw=1 live) -> f16 wpack[oc][k]:
//   k = kt*32+c;  kt<6: tap=kt>>1, ch j=(kt&1)*32+c;  kt=6: c<3 -> x tap c.
// ---------------------------------------------------------------------------
__global__ void pack_w_kernel(const float* __restrict__ conv_w, f16* __restrict__ wpack) {
    int idx = blockIdx.x * 256 + threadIdx.x;
    if (idx >= 4 * 64 * KPK) return;
    int k  = idx % KPK;
    int oc = idx / KPK;
    int kt = k >> 5, c = k & 31;
    float w = 0.0f;
    if (kt < 6) {
        int tap = kt >> 1;
        int j   = (kt & 1) * 32 + c;
        w = conv_w[((oc * 65 + 1 + j) * 3 + tap) * 3 + 1];
    } else if (c < 3) {
        w = conv_w[((oc * 65 + 0) * 3 + c) * 3 + 1];
    }
    wpack[oc * KPK + k] = (f16)w;
}

__device__ __forceinline__ float sigmoid_f(float v) { return 1.0f / (1.0f + __expf(-v)); }
__device__ __forceinline__ float tanh_f(float v) { float e = __expf(2.0f * v); return 1.0f - 2.0f / (e + 1.0f); }

// ---------------------------------------------------------------------------
// Self-contained ConvLSTM: 512 independent blocks, NO inter-block sync.
// Block = 256 thr (4 waves), batch b, valid outputs [n0, n0+128), computes
// a fixed 160-row window [n0-16, n0+144) every step; the outer shell is
// garbage that shrinks inward 1 row/step and is never read for valid rows.
// h rows masked to 0 outside [0,NNP) (zero-padding semantics). Weights, bias
// and c(t) live in registers for all 16 steps; h ping-pongs between two
// swizzled LDS buffers. Wave w: hid [w*16,w*16+16) x 4 gates (one MFMA
// N-subtile per gate) -> fully lane-local epilogue.
// ---------------------------------------------------------------------------
__global__ __launch_bounds__(256, 2)
void lstm_kernel(const float* __restrict__ x, const f16* __restrict__ wpack,
                 const float* __restrict__ conv_b, f16* __restrict__ h_out)
{
    __shared__ __align__(16) f16 hlds[2][HROWS * 64];
    __shared__ __align__(16) f16 xt[WCMP * 8];

    const int blk  = blockIdx.x;
    const int b    = blk >> 5;
    const int tau  = blk & 31;
    const int n0   = tau * WOUT;
    const int tid  = threadIdx.x;
    const int lane = tid & 63;
    const int wave = tid >> 6;
    const int m    = lane & 15;
    const int kg   = lane >> 4;
    const int hid_col = wave * 16 + m;

    // B fragments: 7 k-tiles x 4 gates, resident for all steps
    half8 bf[7][4];
#pragma unroll
    for (int kt = 0; kt < 7; ++kt)
#pragma unroll
        for (int g = 0; g < 4; ++g)
            bf[kt][g] = *(const half8*)(wpack + (g * 64 + hid_col) * KPK + kt * 32 + kg * 8);

    float bias[4];
#pragma unroll
    for (int g = 0; g < 4; ++g) bias[g] = conv_b[g * 64 + hid_col];

    // c in registers: creg[ms*4+r] <-> pos n0-HALO + ms*16 + kg*4 + r
    float creg[40];
#pragma unroll
    for (int i = 0; i < 40; ++i) creg[i] = 0.0f;

    // zero both h buffers (h(0)=0; rows 0/161 stay 0 forever) and xt
    for (int i = tid; i < HROWS * 64; i += 256) { hlds[0][i] = (f16)0; hlds[1][i] = (f16)0; }
    for (int i = tid; i < WCMP * 4; i += 256) ((unsigned*)xt)[i] = 0u;
    __syncthreads();

#pragma unroll 1
    for (int s = 0; s < TSN; ++s) {
        const f16* hrd = hlds[s & 1];
        f16*       hwr = hlds[(s & 1) ^ 1];

        // stage x(s): xt row r <-> pos p = n0-HALO+r, taps p-1,p,p+1 (chunk 0)
        {
            const float* xb = x + ((size_t)b * TSN + s) * NNP;
            for (int r = tid; r < WCMP; r += 256) {
                int p = n0 - HALO + r;
                float v0 = (p - 1 >= 0 && p - 1 < NNP) ? xb[p - 1] : 0.0f;
                float v1 = (p >= 0 && p < NNP) ? xb[p] : 0.0f;
                float v2 = (p + 1 >= 0 && p + 1 < NNP) ? xb[p + 1] : 0.0f;
                ((unsigned*)xt)[r * 4] = f16pair(v0, v1);
                xt[r * 8 + 2] = (f16)v2;
            }
        }
        __syncthreads();   // barrier 1: staging done, prev-step xt readers done

#pragma unroll
        for (int ms = 0; ms < 10; ++ms) {
            const int ar = ms * 16 + m;    // compute-window row of this lane

            floatx4 acc[4];
#pragma unroll
            for (int g = 0; g < 4; ++g) acc[g] = (floatx4){0.f, 0.f, 0.f, 0.f};

#pragma unroll
            for (int kt = 0; kt < 6; ++kt) {
                // h row rr = ar + tap  (h row 0 <-> pos n0-HALO-1)
                half8 a = *(const half8*)(hrd + hadr(ar + (kt >> 1), (kt & 1) * 4 + kg));
#pragma unroll
                for (int g = 0; g < 4; ++g)
                    acc[g] = __builtin_amdgcn_mfma_f32_16x16x32_f16(a, bf[kt][g], acc[g], 0, 0, 0);
            }
            {
                // x k-tile: all kg read chunk 0 of row ar; k>=3 weights are 0
                half8 a = *(const half8*)(xt + ar * 8);
#pragma unroll
                for (int g = 0; g < 4; ++g)
                    acc[g] = __builtin_amdgcn_mfma_f32_16x16x32_f16(a, bf[6][g], acc[g], 0, 0, 0);
            }

            // epilogue: lane owns (4 rows, hid_col, all gates)
#pragma unroll
            for (int r = 0; r < 4; ++r) {
                int ridx = ms * 4 + r;
                float gi = acc[0][r] + bias[0];
                float gf = acc[1][r] + bias[1];
                float go = acc[2][r] + bias[2];
                float gg = acc[3][r] + bias[3];
                float cn = sigmoid_f(gf) * creg[ridx] + sigmoid_f(gi) * tanh_f(gg);
                float hnf = sigmoid_f(go) * tanh_f(cn);
                creg[ridx] = cn;
                int rit = ms * 16 + kg * 4 + r;        // compute-window row
                int pos = n0 - HALO + rit;
                if (pos < 0 || pos >= NNP) hnf = 0.0f; // zero-padding semantics
                float po = __shfl_xor(hnf, 1);         // partner hid_col^1
                if (!(m & 1)) {                        // even lane packs dword
                    int rr = rit + 1;
                    int c  = hid_col >> 3;
                    ((unsigned*)hwr)[rr * 32 + (c ^ (rr & 7)) * 4 + ((m & 7) >> 1)] =
                        f16pair(hnf, po);
                }
            }
        }
        __syncthreads();   // barrier 2: hwr complete before it becomes hrd
    }

    // final h(16) is in hlds[0]; valid rows: pos n0+row <-> rr = row+HALO+1.
    // Coalesced b128 stores (wave writes 1 KiB contiguous).
    for (int i = tid; i < WOUT * 8; i += 256) {
        int row = i >> 3, c = i & 7;
        half8 v = *(const half8*)(hlds[0] + hadr(row + HALO + 1, c));
        *(half8*)(h_out + ((size_t)b * NNP + n0 + row) * HID + c * 8) = v;
    }
}

// ---------------------------------------------------------------------------
// fc: out[b,t,n] = sum_hid h[b][n][hid]*fc_w[hid] + fc_b, broadcast over t
// ---------------------------------------------------------------------------
__global__ void fc_kernel(const f16* __restrict__ h, const float* __restrict__ fc_w,
                          const float* __restrict__ fc_b, float* __restrict__ out) {
    int idx = blockIdx.x * 256 + threadIdx.x;      // b*NNP + n
    const half8* hp = (const half8*)(h + (size_t)idx * HID);
    float s = 0.0f;
#pragma unroll
    for (int q = 0; q < 8; ++q) {
        half8 v = hp[q];
#pragma unroll
        for (int e = 0; e < 8; ++e) s += (float)v[e] * fc_w[q * 8 + e];
    }
    s += fc_b[0];
    int b = idx >> 12, n = idx & (NNP - 1);
#pragma unroll
    for (int t = 0; t < TSN; ++t) out[((size_t)b * TSN + t) * NNP + n] = s;
}

extern "C" void kernel_launch(void* const* d_in, const int* in_sizes, int n_in,
                              void* d_out, int out_size, void* d_ws, size_t ws_size,
                              hipStream_t stream) {
    const float* x      = (const float*)d_in[0];
    const float* conv_w = (const float*)d_in[1];
    const float* conv_b = (const float*)d_in[2];
    const float* fc_w   = (const float*)d_in[3];
    const float* fc_b   = (const float*)d_in[4];
    float* out = (float*)d_out;

    char* ws = (char*)d_ws;
    f16* wpack = (f16*)ws;                    // 4*64*224*2 = 112 KiB
    f16* h_a   = (f16*)(ws + 131072);         // 8.39 MB

    pack_w_kernel<<<(4 * 64 * KPK + 255) / 256, 256, 0, stream>>>(conv_w, wpack);
    lstm_kernel<<<BB * NTIL, 256, 0, stream>>>(x, wpack, conv_b, h_a);
    fc_kernel<<<BB * NNP / 256, 256, 0, stream>>>(h_a, fc_w, fc_b, out);
}